// Round 5
// baseline (1074.239 us; speedup 1.0000x reference)
//
#include <hip/hip_runtime.h>
#include <hip/hip_bf16.h>

static constexpr int HN = 32;     // Hemb == Hgcn == 32
static constexpr int NIN = 128;
static constexpr int NB2 = 2048;  // pass1 grid
static constexpr int NB4 = 8192;  // pass2 grid

__device__ __forceinline__ float bf2f(unsigned short u) {
    union { unsigned int i; float f; } v;
    v.i = ((unsigned int)u) << 16;
    return v.f;
}
__device__ __forceinline__ float ldf(const void* p, size_t i, int isbf) {
    return isbf ? bf2f(((const unsigned short*)p)[i]) : ((const float*)p)[i];
}

// K0: bf16-vs-fp32 input sniff (kept as cheap insurance; expected fp32).
__global__ void detect_kernel(const unsigned int* __restrict__ xw,
                              int* __restrict__ flag)
{
    int lane = threadIdx.x;          // 64 threads
    int hits = 0;
    #pragma unroll
    for (int k = 0; k < 2; ++k) {
        unsigned int w = xw[lane + 64 * k];
        float a = bf2f((unsigned short)(w & 0xFFFFu));
        float aa = fabsf(a);
        if (a == 0.0f || (aa >= 0.000244140625f && aa <= 32.0f)) hits++;
    }
    #pragma unroll
    for (int m = 32; m; m >>= 1) hits += __shfl_xor(hits, m, 64);
    if (lane == 0) flag[0] = (hits >= 64) ? 1 : 0;
}

// K1: h = relu(x @ Wemb + bemb) -> fp32; hw = h @ Wgcn -> fp32.
__global__ __launch_bounds__(256) void embed_kernel(
    const void* __restrict__ x,
    const void* __restrict__ Wemb,
    const void* __restrict__ bemb,
    const void* __restrict__ Wgcn,
    const int* __restrict__ flagp,
    float* __restrict__ h, float* __restrict__ hw, int N)
{
    __shared__ float We[NIN * HN];
    __shared__ float Wg[HN * HN];
    __shared__ float be[HN];
    __shared__ float xs[32][NIN];
    __shared__ float hs[32][HN + 1];
    const int tid = threadIdx.x;
    const int isbf = flagp[0];

    for (int i = tid; i < NIN * HN; i += 256) We[i] = ldf(Wemb, i, isbf);
    for (int i = tid; i < HN * HN; i += 256) Wg[i] = ldf(Wgcn, i, isbf);
    if (tid < HN) be[tid] = ldf(bemb, tid, isbf);

    const int n0 = blockIdx.x * 32;
    if (isbf) {
        const ushort4* x4 = (const ushort4*)((const unsigned short*)x + (size_t)n0 * NIN);
        for (int i = tid; i < 32 * (NIN / 4); i += 256) {
            ushort4 u = x4[i];
            int base = i * 4, n = base >> 7, k = base & (NIN - 1);
            xs[n][k] = bf2f(u.x); xs[n][k + 1] = bf2f(u.y);
            xs[n][k + 2] = bf2f(u.z); xs[n][k + 3] = bf2f(u.w);
        }
    } else {
        const float4* x4 = (const float4*)((const float*)x + (size_t)n0 * NIN);
        for (int i = tid; i < 32 * (NIN / 4); i += 256) {
            float4 u = x4[i];
            int base = i * 4, n = base >> 7, k = base & (NIN - 1);
            xs[n][k] = u.x; xs[n][k + 1] = u.y;
            xs[n][k + 2] = u.z; xs[n][k + 3] = u.w;
        }
    }
    __syncthreads();

    const int f = tid & 31, ns = tid >> 5;   // ns in 0..7
    float a0 = be[f], a1 = be[f], a2 = be[f], a3 = be[f];
    #pragma unroll 8
    for (int k = 0; k < NIN; ++k) {
        float w = We[k * HN + f];
        a0 += xs[ns +  0][k] * w;
        a1 += xs[ns +  8][k] * w;
        a2 += xs[ns + 16][k] * w;
        a3 += xs[ns + 24][k] * w;
    }
    a0 = fmaxf(a0, 0.f); a1 = fmaxf(a1, 0.f);
    a2 = fmaxf(a2, 0.f); a3 = fmaxf(a3, 0.f);
    hs[ns][f] = a0; hs[ns + 8][f] = a1; hs[ns + 16][f] = a2; hs[ns + 24][f] = a3;
    if (n0 + ns      < N) h[(size_t)(n0 + ns     ) * HN + f] = a0;
    if (n0 + ns +  8 < N) h[(size_t)(n0 + ns +  8) * HN + f] = a1;
    if (n0 + ns + 16 < N) h[(size_t)(n0 + ns + 16) * HN + f] = a2;
    if (n0 + ns + 24 < N) h[(size_t)(n0 + ns + 24) * HN + f] = a3;
    __syncthreads();

    float g0 = 0.f, g1 = 0.f, g2 = 0.f, g3 = 0.f;
    #pragma unroll
    for (int k = 0; k < HN; ++k) {
        float w = Wg[k * HN + f];
        g0 += hs[ns][k] * w;      g1 += hs[ns + 8][k] * w;
        g2 += hs[ns + 16][k] * w; g3 += hs[ns + 24][k] * w;
    }
    if (n0 + ns      < N) hw[(size_t)(n0 + ns     ) * HN + f] = g0;
    if (n0 + ns +  8 < N) hw[(size_t)(n0 + ns +  8) * HN + f] = g1;
    if (n0 + ns + 16 < N) hw[(size_t)(n0 + ns + 16) * HN + f] = g2;
    if (n0 + ns + 24 < N) hw[(size_t)(n0 + ns + 24) * HN + f] = g3;
}

// K2 (pass1): per-edge dot (fp32, shuffle tree) -> running max; deg[col]++.
__global__ __launch_bounds__(256) void pass1_kernel(
    const float* __restrict__ h,
    const int* __restrict__ row, const int* __restrict__ col,
    int* __restrict__ deg, float* __restrict__ bmax, int E)
{
    const int lane = threadIdx.x & 31;
    const int gid = (blockIdx.x * 256 + threadIdx.x) >> 5;
    const int ngrp = (gridDim.x * 256) >> 5;
    float lmax = -INFINITY;
    for (int e = gid; e < E; e += ngrp) {
        int r = row[e], c = col[e];
        float p = h[(size_t)r * HN + lane] * h[(size_t)c * HN + lane];
        #pragma unroll
        for (int m = 16; m; m >>= 1) p += __shfl_xor(p, m, 32);
        lmax = fmaxf(lmax, p);
        if (lane == 0) atomicAdd(&deg[c], 1);
    }
    #pragma unroll
    for (int m = 32; m; m >>= 1) lmax = fmaxf(lmax, __shfl_xor(lmax, m, 64));
    __shared__ float sm[4];
    if ((threadIdx.x & 63) == 0) sm[threadIdx.x >> 6] = lmax;
    __syncthreads();
    if (threadIdx.x == 0)
        bmax[blockIdx.x] = fmaxf(fmaxf(sm[0], sm[1]), fmaxf(sm[2], sm[3]));
}

// K3: global max
__global__ __launch_bounds__(256) void max_kernel(
    const float* __restrict__ bmax, float* __restrict__ amax)
{
    float m = -INFINITY;
    for (int i = threadIdx.x; i < NB2; i += 256) m = fmaxf(m, bmax[i]);
    #pragma unroll
    for (int s = 32; s; s >>= 1) m = fmaxf(m, __shfl_xor(m, s, 64));
    __shared__ float sm[4];
    if ((threadIdx.x & 63) == 0) sm[threadIdx.x >> 6] = m;
    __syncthreads();
    if (threadIdx.x == 0) amax[0] = fmaxf(fmaxf(sm[0], sm[1]), fmaxf(sm[2], sm[3]));
}

// K4 (pass2): recompute dot identically; a = expf(dot - amax); deno/znum
// atomics (first chunk only); agg[col] += dis[row]*hw[row] for col in [c0,c1).
__global__ __launch_bounds__(256) void pass2_kernel(
    const float* __restrict__ h, const float* __restrict__ hw,
    const int* __restrict__ row, const int* __restrict__ col,
    const void* __restrict__ t, const int* __restrict__ flagp,
    const float* __restrict__ amax, const int* __restrict__ deg,
    float* __restrict__ deno, float* __restrict__ znum,
    float* __restrict__ agg, int c0, int c1, int dofirst, int E)
{
    const int lane = threadIdx.x & 31;
    const int gid = (blockIdx.x * 256 + threadIdx.x) >> 5;
    const int ngrp = (gridDim.x * 256) >> 5;
    const int isbf = flagp[0];
    const float am = amax[0];
    for (int e = gid; e < E; e += ngrp) {
        int r = row[e], c = col[e];
        if (dofirst) {
            float p = h[(size_t)r * HN + lane] * h[(size_t)c * HN + lane];
            #pragma unroll
            for (int m = 16; m; m >>= 1) p += __shfl_xor(p, m, 32);
            if (lane == 0) {
                float a = expf(p - am);
                unsafeAtomicAdd(&deno[r], a);
                unsafeAtomicAdd(&znum[r], a * ldf(t, c, isbf));
            }
        }
        if (c >= c0 && c < c1) {
            float dis = rsqrtf((float)deg[r] + 1.0f);
            float v = dis * hw[(size_t)r * HN + lane];
            unsafeAtomicAdd(&agg[(size_t)(c - c0) * HN + lane], v);
        }
    }
}

// K5: gcn/rep/z + FF head for nodes [c0,c1); ***fp32 output stores***.
__global__ __launch_bounds__(256) void final_kernel(
    const float* __restrict__ h, const float* __restrict__ hw,
    const float* __restrict__ agg,
    const int* __restrict__ deg, const float* __restrict__ deno,
    const float* __restrict__ znum,
    const void* __restrict__ t,
    const void* __restrict__ bgcn,
    const void* __restrict__ W1, const void* __restrict__ b1,
    const void* __restrict__ W2, const void* __restrict__ b2,
    const int* __restrict__ flagp,
    float* __restrict__ out0,
    float* __restrict__ outr,
    float* __restrict__ outz, int c0, int c1)
{
    __shared__ float W1s[34 * HN];
    __shared__ float b1s[HN], W2s[HN], bgs[HN];
    __shared__ float b2s;
    const int tid = threadIdx.x;
    const int isbf = flagp[0];
    for (int i = tid; i < 34 * HN; i += 256) W1s[i] = ldf(W1, i, isbf);
    if (tid < HN) {
        b1s[tid] = ldf(b1, tid, isbf);
        W2s[tid] = ldf(W2, tid, isbf);
        bgs[tid] = ldf(bgcn, tid, isbf);
    }
    if (tid == 0) b2s = ldf(b2, 0, isbf);
    __syncthreads();

    const int lane = tid & 31;
    const int v = c0 + blockIdx.x * 8 + (tid >> 5);
    if (v >= c1) return;

    float aj = agg[(size_t)(v - c0) * HN + lane];
    float wj = hw[(size_t)v * HN + lane];
    float hj = h[(size_t)v * HN + lane];
    float dis = rsqrtf((float)deg[v] + 1.0f);
    float gcn = dis * aj + dis * dis * wj + bgs[lane];
    float rep = hj + fmaxf(gcn, 0.f);
    float z = znum[v] / (deno[v] + 1e-8f);
    float tv = ldf(t, v, isbf);

    float acc = b1s[lane] + tv * W1s[32 * HN + lane] + z * W1s[33 * HN + lane];
    #pragma unroll
    for (int k = 0; k < HN; ++k)
        acc += __shfl(rep, k, 32) * W1s[k * HN + lane];
    float f1 = fmaxf(acc, 0.f);
    float o = f1 * W2s[lane];
    #pragma unroll
    for (int m = 16; m; m >>= 1) o += __shfl_xor(o, m, 32);

    outr[(size_t)v * HN + lane] = rep;
    if (lane == 0) {
        out0[v] = o + b2s;
        outz[v] = z;
    }
}

extern "C" void kernel_launch(void* const* d_in, const int* in_sizes, int n_in,
                              void* d_out, int out_size, void* d_ws, size_t ws_size,
                              hipStream_t stream)
{
    const int N = out_size / 34;   // out[N] + rep[N*32] + z[N]
    const int E = in_sizes[2];

    const void* x    = d_in[0];
    const void* t    = d_in[1];
    const int* row   = (const int*)d_in[2];
    const int* col   = (const int*)d_in[3];
    const void* Wemb = d_in[4];
    const void* bemb = d_in[5];
    const void* Wgcn = d_in[6];
    const void* bgcn = d_in[7];
    const void* W1   = d_in[8];
    const void* b1   = d_in[9];
    const void* W2   = d_in[10];
    const void* b2   = d_in[11];

    // ws layout (fp32): h | hw | bmax | amax | flag | deno | znum | deg
    //                   | agg (chunk-sized remainder)
    char* wsb = (char*)d_ws;
    size_t off = 0;
    float* h    = (float*)(wsb + off); off += (size_t)N * HN * 4;
    float* hw   = (float*)(wsb + off); off += (size_t)N * HN * 4;
    float* bmax = (float*)(wsb + off); off += (size_t)NB2 * 4;
    float* amax = (float*)(wsb + off); off += 4;
    int*   flag = (int*)(wsb + off);   off += 4;
    off = (off + 15) & ~(size_t)15;
    float* deno = (float*)(wsb + off); off += (size_t)N * 4;
    float* znum = (float*)(wsb + off); off += (size_t)N * 4;
    int*   deg  = (int*)(wsb + off);   off += (size_t)N * 4;
    off = (off + 255) & ~(size_t)255;
    float* agg  = (float*)(wsb + off);

    size_t avail = (ws_size > off) ? (ws_size - off) : 0;
    int C = (int)((avail / ((size_t)HN * 4) < (size_t)N) ? (avail / ((size_t)HN * 4))
                                                         : (size_t)N);
    if (C <= 0) C = N;
    const int nchunks = (N + C - 1) / C;

    hipMemsetAsync(deno, 0, (size_t)N * 12, stream);   // deno, znum, deg

    detect_kernel<<<1, 64, 0, stream>>>((const unsigned int*)x, flag);
    embed_kernel<<<(N + 31) / 32, 256, 0, stream>>>(x, Wemb, bemb, Wgcn, flag,
                                                    h, hw, N);
    pass1_kernel<<<NB2, 256, 0, stream>>>(h, row, col, deg, bmax, E);
    max_kernel<<<1, 256, 0, stream>>>(bmax, amax);

    float* outp = (float*)d_out;
    for (int k = 0; k < nchunks; ++k) {
        int c0 = k * C;
        int c1 = (c0 + C < N) ? (c0 + C) : N;
        hipMemsetAsync(agg, 0, (size_t)(c1 - c0) * HN * 4, stream);
        pass2_kernel<<<NB4, 256, 0, stream>>>(h, hw, row, col, t, flag,
                                              amax, deg, deno, znum, agg,
                                              c0, c1, (k == 0) ? 1 : 0, E);
        final_kernel<<<(c1 - c0 + 7) / 8, 256, 0, stream>>>(
            h, hw, agg, deg, deno, znum, t, bgcn, W1, b1, W2, b2, flag,
            outp, outp + N, outp + (size_t)N * 33, c0, c1);
    }
}